// Round 3
// baseline (207.987 us; speedup 1.0000x reference)
//
#include <hip/hip_runtime.h>
#include <hip/hip_fp16.h>

#define N_NODES    100000
#define N_EDGES    3200000
#define IN_DIM     128
#define EMB        32
#define NUM_GRAPHS 256

#define FB         1024      // coarse buckets (782 used: bucket = dst >> 7)
#define NODES_PB   128       // nodes per bucket
#define NBUCKETS   782       // ceil(N_NODES / 128)
#define FB_B       512       // fill blocks
#define FB_EPB     6250      // 512 * 6250 == N_EDGES
#define NCHUNK     16        // block-dim prefix chunks (32 rows each)
#define CHROWS     32
#define XW_BLOCKS  1563      // ceil(N_NODES / 64)
#define CAP        5632      // k_fg LDS staging (mean 4092, +24 sigma)
#define GMAX       4         // graphs spanned by a 128-node window (~390/graph)

typedef _Float16 half8 __attribute__((ext_vector_type(8)));
typedef float floatx4 __attribute__((ext_vector_type(4)));

// ---------------------------------------------------------------------------
// Per-block histogram of dst>>7, written as a coalesced private row (NO global
// atomics). bhist[FB_B][FB]. Rows are reused by k_fill (no second hist pass).
// ---------------------------------------------------------------------------
__global__ __launch_bounds__(512) void k_hist(const int* __restrict__ ei,
                                              int* __restrict__ bhist) {
    __shared__ int h[FB];
    int t = threadIdx.x;
    for (int i = t; i < FB; i += 512) h[i] = 0;
    __syncthreads();
    int e0 = blockIdx.x * FB_EPB;
    for (int e = e0 + t; e < e0 + FB_EPB; e += 512)
        atomicAdd(&h[ei[N_EDGES + e] >> 7], 1);
    __syncthreads();
    for (int i = t; i < FB; i += 512) bhist[blockIdx.x * FB + i] = h[i];
}

// ---------------------------------------------------------------------------
// Blocks 0..15: part[j][b] = sum of bhist rows in chunk j (32 rows).
// Block 16: zero sums + per-graph counts (folded aux work, saves a launch).
// ---------------------------------------------------------------------------
__global__ __launch_bounds__(512) void k_part(const int* __restrict__ bhist,
                                              int* __restrict__ part,
                                              const int* __restrict__ batch,
                                              float* __restrict__ sums,
                                              float* __restrict__ counts) {
    int j = blockIdx.x, t = threadIdx.x;
    if (j == NCHUNK) {
        for (int i = t; i < NUM_GRAPHS * EMB; i += 512) sums[i] = 0.f;
        if (t < NUM_GRAPHS) {
            int lo = 0, hi = N_NODES;
            while (lo < hi) { int mid = (lo + hi) >> 1; if (batch[mid] < t) lo = mid + 1; else hi = mid; }
            int a = lo;
            lo = 0; hi = N_NODES;
            int g1 = t + 1;
            while (lo < hi) { int mid = (lo + hi) >> 1; if (batch[mid] < g1) lo = mid + 1; else hi = mid; }
            counts[t] = (float)(lo - a);
        }
        return;
    }
    int row0 = j * CHROWS;
    for (int b = t; b < FB; b += 512) {
        int acc = 0;
#pragma unroll 8
        for (int i = 0; i < CHROWS; ++i) acc += bhist[(row0 + i) * FB + b];
        part[j * FB + b] = acc;
    }
}

// ---------------------------------------------------------------------------
// Each of 16 blocks redundantly computes bucket totals from part[] + the
// 1024-bucket exclusive scan (cbase), then writes the deterministic per-row
// bases bbase[row][b] for its own 32-row chunk. Block 0 also publishes cbase.
// ---------------------------------------------------------------------------
__global__ __launch_bounds__(1024) void k_mid(const int* __restrict__ bhist,
                                              const int* __restrict__ part,
                                              int* __restrict__ bbase,
                                              int* __restrict__ cbase) {
    __shared__ int ts[FB];
    int b = threadIdx.x;      // bucket
    int j = blockIdx.x;       // chunk (uniform)
    int tot = 0;
#pragma unroll
    for (int k = 0; k < NCHUNK; ++k) tot += part[k * FB + b];
    ts[b] = tot;
    __syncthreads();
    for (int off = 1; off < FB; off <<= 1) {
        int u = (b >= off) ? ts[b - off] : 0;
        __syncthreads();
        ts[b] += u;
        __syncthreads();
    }
    int cb = ts[b] - tot;     // exclusive over buckets
    if (j == 0) {
        cbase[b] = cb;
        if (b == 0) cbase[FB] = N_EDGES;
    }
    int run = cb;
    for (int k = 0; k < j; ++k) run += part[k * FB + b];   // L2-hot re-read
    int row0 = j * CHROWS;
    for (int i = 0; i < CHROWS; ++i) {
        int h = bhist[(row0 + i) * FB + b];
        bbase[(row0 + i) * FB + b] = run;
        run += h;
    }
}

// ---------------------------------------------------------------------------
// Scatter pass, LDS-staged counting sort (bucket granularity):
//   1. own bhist row -> in-block scan -> local bases
//   2. single edge pass: rec + global dest staged in LDS, bucket-sorted
//   3. write-out: consecutive lanes -> consecutive global addresses
// ---------------------------------------------------------------------------
__global__ __launch_bounds__(512) void k_fill(const int* __restrict__ ei,
                                              const int* __restrict__ bhist,
                                              const int* __restrict__ bbase,
                                              unsigned int* __restrict__ recs) {
    __shared__ unsigned int staged[FB_EPB];   // 25000 B, bucket-sorted records
    __shared__ int dpos[FB_EPB];              // 25000 B, global destinations
    __shared__ int hd[FB];                    // hist, then delta = bbase - lbase
    __shared__ int cur[FB];                   // running local cursor
    __shared__ int ts[512];                   // scan scratch
    int t = threadIdx.x;
    int rowoff = blockIdx.x * FB;
    for (int i = t; i < FB; i += 512) hd[i] = bhist[rowoff + i];
    __syncthreads();
    int v0 = hd[2 * t], v1 = hd[2 * t + 1];
    int tot = v0 + v1;
    ts[t] = tot;
    __syncthreads();
    for (int off = 1; off < 512; off <<= 1) {
        int u = (t >= off) ? ts[t - off] : 0;
        __syncthreads();
        ts[t] += u;
        __syncthreads();
    }
    int lb0 = ts[t] - tot;     // exclusive local base, bucket 2t
    int lb1 = lb0 + v0;        // bucket 2t+1
    cur[2 * t] = lb0;
    cur[2 * t + 1] = lb1;
    hd[2 * t]     = bbase[rowoff + 2 * t]     - lb0;
    hd[2 * t + 1] = bbase[rowoff + 2 * t + 1] - lb1;
    __syncthreads();
    int e0 = blockIdx.x * FB_EPB;
    for (int e = e0 + t; e < e0 + FB_EPB; e += 512) {
        int s = ei[e];
        int d = ei[N_EDGES + e];
        int b = d >> 7;
        int lpos = atomicAdd(&cur[b], 1);
        staged[lpos] = ((unsigned int)(d & 127) << 24) | (unsigned int)s;
        dpos[lpos] = lpos + hd[b];
    }
    __syncthreads();
    for (int j = t; j < FB_EPB; j += 512)
        recs[dpos[j]] = staged[j];
}

// ---------------------------------------------------------------------------
// k_deg: per-bucket node histogram of recs -> rowstart + dinv ONLY (the sort
// moved into k_fg; edge_src is never materialized). 1 KB LDS, streaming read.
// ---------------------------------------------------------------------------
__global__ __launch_bounds__(512) void k_deg(const unsigned int* __restrict__ recs,
                                             const int* __restrict__ cbase,
                                             int* __restrict__ rowstart,
                                             float* __restrict__ dinv) {
    __shared__ int h2[NODES_PB], sc[NODES_PB];
    int t = threadIdx.x, b = blockIdx.x;
    if (t < NODES_PB) h2[t] = 0;
    __syncthreads();
    int seg0 = cbase[b];
    int cnt = cbase[b + 1] - seg0;
    for (int j = t; j < cnt; j += 512)
        atomicAdd(&h2[recs[seg0 + j] >> 24], 1);
    __syncthreads();
    int v = 0;
    if (t < NODES_PB) { v = h2[t]; sc[t] = v; }
    __syncthreads();
    for (int off = 1; off < NODES_PB; off <<= 1) {
        int u = 0;
        if (t < NODES_PB && t >= off) u = sc[t - off];
        __syncthreads();
        if (t < NODES_PB) sc[t] += u;
        __syncthreads();
    }
    if (t < NODES_PB) {
        int node = (b << 7) + t;
        if (node < N_NODES) {
            rowstart[node] = seg0 + sc[t] - v;
            dinv[node] = rsqrtf((float)v + 1.0f);
        }
    }
    if (b == 0 && t == 0) rowstart[N_NODES] = N_EDGES;
}

// ---------------------------------------------------------------------------
// xw = (x @ W1) * dinv[row] -> fp16 via MFMA 16x16x32_f16 (one wave = 16
// rows). Runs AFTER k_deg so the dinv scale folds in here.
// ---------------------------------------------------------------------------
__global__ __launch_bounds__(256) void k_xw(const float* __restrict__ x,
                                            const float* __restrict__ W1,
                                            const float* __restrict__ dinv,
                                            __half* __restrict__ xwh) {
    __shared__ _Float16 Wh[IN_DIM * (EMB + 1)];   // 8.25 KB, padded stride 33
    for (int i = threadIdx.x; i < IN_DIM * EMB; i += 256)
        Wh[(i >> 5) * (EMB + 1) + (i & 31)] = (_Float16)W1[i];
    __syncthreads();
    int wave = threadIdx.x >> 6;
    int lane = threadIdx.x & 63;
    int m = lane & 15, quad = lane >> 4;
    int row0 = (blockIdx.x * 4 + wave) * 16;
    if (row0 >= N_NODES) return;
    half8 bfrag[2][4];
#pragma unroll
    for (int nt = 0; nt < 2; ++nt)
#pragma unroll
        for (int ks = 0; ks < 4; ++ks)
#pragma unroll
            for (int j = 0; j < 8; ++j)
                bfrag[nt][ks][j] = Wh[(ks * 32 + quad * 8 + j) * (EMB + 1) + nt * 16 + m];
    const float* xr = x + (size_t)(row0 + m) * IN_DIM + quad * 8;
    floatx4 c0 = {0.f, 0.f, 0.f, 0.f}, c1 = {0.f, 0.f, 0.f, 0.f};
#pragma unroll
    for (int ks = 0; ks < 4; ++ks) {
        float4 a0 = *(const float4*)(xr + ks * 32);
        float4 a1 = *(const float4*)(xr + ks * 32 + 4);
        half8 af;
        af[0] = (_Float16)a0.x; af[1] = (_Float16)a0.y;
        af[2] = (_Float16)a0.z; af[3] = (_Float16)a0.w;
        af[4] = (_Float16)a1.x; af[5] = (_Float16)a1.y;
        af[6] = (_Float16)a1.z; af[7] = (_Float16)a1.w;
        c0 = __builtin_amdgcn_mfma_f32_16x16x32_f16(af, bfrag[0][ks], c0, 0, 0, 0);
        c1 = __builtin_amdgcn_mfma_f32_16x16x32_f16(af, bfrag[1][ks], c1, 0, 0, 0);
    }
#pragma unroll
    for (int r = 0; r < 4; ++r) {
        int ro = row0 + quad * 4 + r;
        float di = dinv[ro];
        xwh[(size_t)ro * EMB + m]      = __float2half(c0[r] * di);
        xwh[(size_t)ro * EMB + 16 + m] = __float2half(c1[r] * di);
    }
}

// ---------------------------------------------------------------------------
// Gather step reading edge srcs from LDS (uniform per 16-lane group ->
// broadcast). OVF path falls back to global scratch (never taken at 24 sigma).
// ---------------------------------------------------------------------------
template<int K, bool OVF>
__device__ __forceinline__ void lstep(const int* __restrict__ srt,
                                      const unsigned int* __restrict__ ovf,
                                      int seg0, const __half2* __restrict__ rows,
                                      int cc, int e, float& a0, float& a1) {
    int s[K];
    float2 f[K];
#pragma unroll
    for (int k = 0; k < K; ++k) {
        int idx = e + k;
        if (OVF) s[k] = (idx < CAP) ? srt[idx] : (int)ovf[seg0 + idx];
        else     s[k] = srt[idx];
    }
#pragma unroll
    for (int k = 0; k < K; ++k) f[k] = __half22float2(rows[(size_t)s[k] * 16 + cc]);
#pragma unroll
    for (int k = 0; k < K; ++k) { a0 += f[k].x; a1 += f[k].y; }
}

template<bool OVF>
__device__ __forceinline__ void node_gather(const int* __restrict__ srt,
                                            const unsigned int* __restrict__ ovf,
                                            int seg0, const __half2* __restrict__ rows,
                                            int cc, int e0, int e1, float& a0, float& a1) {
    int e = e0;
    for (; e + 16 <= e1; e += 16) lstep<16, OVF>(srt, ovf, seg0, rows, cc, e, a0, a1);
    if (e + 8 <= e1) { lstep<8, OVF>(srt, ovf, seg0, rows, cc, e, a0, a1); e += 8; }
    if (e + 4 <= e1) { lstep<4, OVF>(srt, ovf, seg0, rows, cc, e, a0, a1); e += 4; }
    if (e + 2 <= e1) { lstep<2, OVF>(srt, ovf, seg0, rows, cc, e, a0, a1); e += 2; }
    if (e < e1)      { lstep<1, OVF>(srt, ovf, seg0, rows, cc, e, a0, a1); }
}

// ---------------------------------------------------------------------------
// Fused sort+gather: one block per 128-node bucket. rowstart gives exact
// per-node cursors -> single recs pass places node-sorted srcs in LDS; gather
// runs from LDS (no edge_src round trip). Epilogue: self-loop + tanh +
// per-graph LDS pooling (128-node runs -> ~2 graphs/block -> few atomics).
// ---------------------------------------------------------------------------
__global__ __launch_bounds__(512) void k_fg(const unsigned int* __restrict__ recs,
                                            const int* __restrict__ rowstart,
                                            const __half* __restrict__ xwh,
                                            const int* __restrict__ batch,
                                            const float* __restrict__ b1,
                                            float* __restrict__ sums,
                                            unsigned int* __restrict__ ovf) {
    __shared__ int srt[CAP];                 // 22 KB node-sorted srcs
    __shared__ int rs[NODES_PB + 1];
    __shared__ int cur[NODES_PB];
    __shared__ float gsum[GMAX][EMB];        // per-graph accumulators
    __shared__ int gfirst;
    int t = threadIdx.x, b = blockIdx.x;
    int node0 = b << 7;
    if (t <= NODES_PB)
        rs[t] = (node0 + t <= N_NODES) ? rowstart[node0 + t] : N_EDGES;
    if (t < GMAX * EMB) ((float*)gsum)[t] = 0.f;
    if (t == 0) gfirst = batch[node0];
    __syncthreads();
    if (t < NODES_PB) cur[t] = rs[t];
    int seg0 = rs[0];
    int cnt = rs[NODES_PB] - seg0;
    __syncthreads();
    // node-granularity counting sort into LDS
    for (int j = t; j < cnt; j += 512) {
        unsigned int r = recs[seg0 + j];
        int gp = atomicAdd(&cur[r >> 24], 1);   // global sorted position
        int lp = gp - seg0;
        int s = (int)(r & 0x00FFFFFF);
        if (lp < CAP) srt[lp] = s;
        else          ovf[gp] = (unsigned int)s;   // dead-scratch fallback
    }
    __syncthreads();
    bool has_ovf = (cnt > CAP);
    const __half2* rows = (const __half2*)xwh;   // row stride = 16 half2
    int grp = t >> 4, cc = t & 15;
    float2 bb = *(const float2*)(b1 + 2 * cc);
    int gf = gfirst;
#pragma unroll 1
    for (int rep = 0; rep < 4; ++rep) {
        int li = rep * 32 + grp;
        int i = node0 + li;
        if (i < N_NODES) {
            int e0 = rs[li] - seg0, e1 = rs[li + 1] - seg0;
            float a0 = 0.f, a1 = 0.f;
            if (has_ovf) node_gather<true >(srt, ovf, seg0, rows, cc, e0, e1, a0, a1);
            else         node_gather<false>(srt, ovf, seg0, rows, cc, e0, e1, a0, a1);
            float di = rsqrtf((float)(e1 - e0) + 1.0f);
            float2 fs = __half22float2(rows[(size_t)i * 16 + cc]);
            float h0 = tanhf((a0 + fs.x) * di + bb.x);
            float h1 = tanhf((a1 + fs.y) * di + bb.y);
            int g = batch[i];
            int gl = g - gf;
            if (gl >= 0 && gl < GMAX) {
                atomicAdd(&gsum[gl][2 * cc], h0);
                atomicAdd(&gsum[gl][2 * cc + 1], h1);
            } else {
                atomicAdd(&sums[g * EMB + 2 * cc], h0);
                atomicAdd(&sums[g * EMB + 2 * cc + 1], h1);
            }
        }
    }
    __syncthreads();
    if (t < GMAX * EMB) {
        int gl = t >> 5, col = t & 31;
        float v = gsum[gl][col];
        int g = gf + gl;
        if (v != 0.f && g < NUM_GRAPHS) atomicAdd(&sums[g * EMB + col], v);
    }
}

// ---------------------------------------------------------------------------
// head: out[g] = [sums, means] @ Wout + bout
// ---------------------------------------------------------------------------
__global__ __launch_bounds__(64) void k_out(const float* __restrict__ sums,
                                            const float* __restrict__ counts,
                                            const float* __restrict__ Wout,
                                            const float* __restrict__ bout,
                                            float* __restrict__ out) {
    int g = blockIdx.x * 64 + threadIdx.x;
    if (g >= NUM_GRAPHS) return;
    float inv = 1.0f / fmaxf(counts[g], 1.0f);
    float acc = bout[0];
#pragma unroll
    for (int c = 0; c < EMB; ++c) {
        float s = sums[g * EMB + c];
        acc += s * Wout[c] + s * inv * Wout[EMB + c];
    }
    out[g] = acc;
}

extern "C" void kernel_launch(void* const* d_in, const int* in_sizes, int n_in,
                              void* d_out, int out_size, void* d_ws, size_t ws_size,
                              hipStream_t stream) {
    const float* x     = (const float*)d_in[0];
    const int*   ei    = (const int*)d_in[1];   // [2, E]
    const int*   batch = (const int*)d_in[2];   // [N], sorted
    const float* W1    = (const float*)d_in[3];
    const float* b1    = (const float*)d_in[4];
    const float* Wout  = (const float*)d_in[5];
    const float* bout  = (const float*)d_in[6];
    float* out = (float*)d_out;

    // workspace (~33 MB)
    char* ws = (char*)d_ws;
    __half* xwh        = (__half*)ws;       ws += (size_t)N_NODES * EMB * sizeof(__half);  // 6.4 MB
    unsigned int* recs = (unsigned int*)ws; ws += (size_t)N_EDGES * sizeof(int);           // 12.8 MB
    unsigned int* escr = (unsigned int*)ws; ws += (size_t)N_EDGES * sizeof(int);           // 12.8 MB scratch
    int*   rowstart    = (int*)ws;          ws += (size_t)(N_NODES + 4) * sizeof(int);     // 0.4 MB
    float* dinv        = (float*)ws;        ws += (size_t)N_NODES * sizeof(float);         // 0.4 MB
    int*   cbase       = (int*)ws;          ws += (FB + 2) * sizeof(int);
    float* sums        = (float*)ws;        ws += (size_t)NUM_GRAPHS * EMB * sizeof(float);
    float* counts      = (float*)ws;

    // Overlays inside escr: bhist (2 MB) + part (64 KB) + bbase (2 MB) are
    // dead after k_fill; the tail doubles as k_fg's overflow fallback.
    int* bhist = (int*)escr;                     // [FB_B][FB]  2 MB
    int* part  = bhist + (size_t)FB_B * FB;      // [NCHUNK][FB] 64 KB
    int* bbase = part + (size_t)NCHUNK * FB;     // [FB_B][FB]  2 MB

    k_hist <<<FB_B, 512, 0, stream>>>(ei, bhist);
    k_part <<<NCHUNK + 1, 512, 0, stream>>>(bhist, part, batch, sums, counts);
    k_mid  <<<NCHUNK, 1024, 0, stream>>>(bhist, part, bbase, cbase);
    k_fill <<<FB_B, 512, 0, stream>>>(ei, bhist, bbase, recs);
    k_deg  <<<NBUCKETS, 512, 0, stream>>>(recs, cbase, rowstart, dinv);
    k_xw   <<<XW_BLOCKS, 256, 0, stream>>>(x, W1, dinv, xwh);
    k_fg   <<<NBUCKETS, 512, 0, stream>>>(recs, rowstart, xwh, batch, b1, sums, escr);
    k_out  <<<(NUM_GRAPHS + 63) / 64, 64, 0, stream>>>(sums, counts, Wout, bout, out);
}